// Round 19
// baseline (94.398 us; speedup 1.0000x reference)
//
#include <hip/hip_runtime.h>

#define BB 16
#define HIMG 64
#define WIMG 64
#define CC 256
#define NHEAD 8
#define HD 32
#define NN 4096
#define PWD 65   // 2*DH+1
#define PADC 264 // qr_bf / attn_bf row stride (ushorts)
#define NCH 32   // k1 chunks per batch (128 rows each)

typedef short bf16x8 __attribute__((ext_vector_type(8)));
typedef float f32x4 __attribute__((ext_vector_type(4)));

__device__ __forceinline__ float elu1(float x) {
    return x > 0.0f ? x + 1.0f : __expf(x);
}
__device__ __forceinline__ float sigm(float x) {
    return 1.0f / (1.0f + __expf(-x));
}
__device__ __forceinline__ unsigned short f2bf(float f) {
    union { float f; unsigned int u; } v; v.f = f;
    unsigned int r = v.u + 0x7FFFu + ((v.u >> 16) & 1u);   // RNE
    return (unsigned short)(r >> 16);
}
__device__ __forceinline__ float bf2f(unsigned short u) {
    union { unsigned int u; float f; } v; v.u = ((unsigned int)u) << 16;
    return v.f;
}

// ---------------- Kernel 0: pw[n][c] = sigmoid(posw[i+1][j+1][c]) ---------------
__global__ __launch_bounds__(256) void k0_pw(
    const float* __restrict__ posw, float* __restrict__ pw)
{
    const int gid = blockIdx.x * 256 + threadIdx.x;  // 0 .. 262143
    const int n = gid >> 6;
    const int p = gid & 63;
    const int ii = n >> 6, jj = n & 63;
    const float4 v = *(const float4*)(posw + (size_t)((ii + 1) * PWD + (jj + 1)) * CC + p * 4);
    float4 r;
    r.x = sigm(v.x); r.y = sigm(v.y); r.z = sigm(v.z); r.w = sigm(v.w);
    *(float4*)(pw + (size_t)n * CC + p * 4) = r;
}

// ---------------- Kernel 1: partial kv — no LDS, no barriers, fragment loads ----
__global__ __launch_bounds__(256) void k1_partial(
    const float* __restrict__ x2, const float* __restrict__ x3,
    const float* __restrict__ pw, float* __restrict__ pkv,
    float* __restrict__ pksum)
{
    const int t     = threadIdx.x;
    const int wv    = t >> 6;              // 0..3 -> heads 2wv, 2wv+1
    const int blk   = blockIdx.x;          // b*NCH + chunk
    const int b     = blk >> 5;
    const int chunk = blk & 31;
    const int l     = t & 63;
    const int lr    = l & 15;              // fragment row/col within 16
    const int lg    = l >> 4;              // k-group: rows lg*8 + j

    const size_t bb = (size_t)b * NN * CC;

    f32x4 acc[2][4];
#pragma unroll
    for (int hh = 0; hh < 2; ++hh)
#pragma unroll
        for (int tl = 0; tl < 4; ++tl)
            acc[hh][tl] = (f32x4){0.f, 0.f, 0.f, 0.f};
    float ks[2][2] = {{0.f, 0.f}, {0.f, 0.f}};

    for (int s = 0; s < 4; ++s) {
        const int n0 = chunk * 128 + s * 32 + lg * 8;   // this lane's row base

        float kf[2][2][8], pf[2][2][8], vf[2][2][8];
#pragma unroll
        for (int hh = 0; hh < 2; ++hh)
#pragma unroll
            for (int dh = 0; dh < 2; ++dh) {
                const int ch = (wv * 2 + hh) * HD + dh * 16 + lr;
                const float* pk = x2 + bb + (size_t)n0 * CC + ch;
#pragma unroll
                for (int j = 0; j < 8; ++j) kf[hh][dh][j] = pk[j * CC];
            }
#pragma unroll
        for (int hh = 0; hh < 2; ++hh)
#pragma unroll
            for (int dh = 0; dh < 2; ++dh) {
                const int ch = (wv * 2 + hh) * HD + dh * 16 + lr;
                const float* pp = pw + (size_t)n0 * CC + ch;
#pragma unroll
                for (int j = 0; j < 8; ++j) pf[hh][dh][j] = pp[j * CC];
            }
#pragma unroll
        for (int hh = 0; hh < 2; ++hh)
#pragma unroll
            for (int eh = 0; eh < 2; ++eh) {
                const int ch = (wv * 2 + hh) * HD + eh * 16 + lr;
                const float* pv = x3 + bb + (size_t)n0 * CC + ch;
#pragma unroll
                for (int j = 0; j < 8; ++j) vf[hh][eh][j] = pv[j * CC];
            }

#pragma unroll
        for (int hh = 0; hh < 2; ++hh) {
            union { bf16x8 v8; unsigned short u[8]; } ka[2], vb[2];
#pragma unroll
            for (int dh = 0; dh < 2; ++dh)
#pragma unroll
                for (int j = 0; j < 8; ++j) {
                    const float e = elu1(kf[hh][dh][j]);
                    ks[hh][dh] += e;
                    ka[dh].u[j] = f2bf(e * pf[hh][dh][j]);
                }
#pragma unroll
            for (int eh = 0; eh < 2; ++eh)
#pragma unroll
                for (int j = 0; j < 8; ++j)
                    vb[eh].u[j] = f2bf(vf[hh][eh][j]);
#pragma unroll
            for (int dh = 0; dh < 2; ++dh)
#pragma unroll
                for (int eh = 0; eh < 2; ++eh)
                    acc[hh][dh * 2 + eh] = __builtin_amdgcn_mfma_f32_16x16x32_bf16(
                        ka[dh].v8, vb[eh].v8, acc[hh][dh * 2 + eh], 0, 0, 0);
        }
    }

#pragma unroll
    for (int hh = 0; hh < 2; ++hh) {
        float* dst = pkv + (size_t)blk * (NHEAD * HD * HD) + (wv * 2 + hh) * (HD * HD);
#pragma unroll
        for (int tl = 0; tl < 4; ++tl)
            *(f32x4*)(dst + tl * 256 + l * 4) = acc[hh][tl];
    }

#pragma unroll
    for (int hh = 0; hh < 2; ++hh)
#pragma unroll
        for (int dh = 0; dh < 2; ++dh) {
            ks[hh][dh] += __shfl_xor(ks[hh][dh], 16);
            ks[hh][dh] += __shfl_xor(ks[hh][dh], 32);
        }
    if (l < 16) {
#pragma unroll
        for (int hh = 0; hh < 2; ++hh)
#pragma unroll
            for (int dh = 0; dh < 2; ++dh)
                pksum[(size_t)blk * CC + (wv * 2 + hh) * HD + dh * 16 + l] = ks[hh][dh];
    }
}

// ---------------- Kernel 2: reduce partials; emit kvbT (bf16, [b][h][e][d]) -----
__global__ __launch_bounds__(256) void k2_reduce(
    const float* __restrict__ pkv, const float* __restrict__ pksum,
    unsigned short* __restrict__ kvbT, float* __restrict__ kmean)
{
    const int gid = blockIdx.x * 256 + threadIdx.x;   // over B*8192
    const int b = gid >> 13;
    const int o = gid & 8191;
    float s = 0.f;
#pragma unroll 4
    for (int c = 0; c < NCH; ++c)
        s += pkv[(size_t)(b * NCH + c) * (NHEAD * HD * HD) + o];
    const int hh   = o >> 10;
    const int r1   = o & 1023;
    const int tile = r1 >> 8;
    const int li   = (r1 >> 2) & 63;
    const int rg   = o & 3;
    const int d    = (tile >> 1) * 16 + (li >> 4) * 4 + rg;
    const int e    = (tile & 1) * 16 + (li & 15);
    kvbT[(((size_t)b * NHEAD + hh) * HD + e) * HD + d] = f2bf(s * (1.0f / NN));
    if (o < CC) {
        float ss = 0.f;
#pragma unroll 4
        for (int c = 0; c < NCH; ++c)
            ss += pksum[(size_t)(b * NCH + c) * CC + o];
        kmean[b * CC + o] = ss * (1.0f / NN);
    }
}

// ---------------- k3a: attn = MFMA((qr*z) @ kv) -> bf16 ws ----------------------
// grid = B*256 (quarter image row each), block = 256 (4 waves).
// Same stage+MFMA as the fused k3 (R16), but epilogue is a coalesced bf16 store
// of attn — the 30-load lepe half moves to the barrier-free k3b.
__global__ __launch_bounds__(256) void k3a_attn(
    const float* __restrict__ x1, const float* __restrict__ pw,
    const unsigned short* __restrict__ kvbT, const float* __restrict__ kmean,
    unsigned short* __restrict__ attn_ws)
{
    const int blk  = blockIdx.x;      // b*256 + irow*4 + jq
    const int b    = blk >> 8;
    const int irow = (blk >> 2) & 63;
    const int jq   = blk & 3;
    const int j0   = jq << 4;
    const int t    = threadIdx.x;

    __shared__ unsigned short qr_bf[16 * PADC];    // 8.4 KiB
    __shared__ unsigned short attn_bf[16 * PADC];  // 8.4 KiB

    // ---- stage: q_rope * z -> bf16 LDS ----
    {
        const int p    = t & 63;
        const int pixo = t >> 6;
        const float4 km4 = *(const float4*)(kmean + b * CC + p * 4);
        const float* x1b = x1 + ((size_t)b * NN + (size_t)irow * 64 + j0) * CC;
        const float* pwb = pw + ((size_t)irow * 64 + j0) * CC;
        float4 xv[4], pvv[4];
#pragma unroll
        for (int s = 0; s < 4; ++s)
            xv[s] = *(const float4*)(x1b + (size_t)(s * 4 + pixo) * CC + p * 4);
#pragma unroll
        for (int s = 0; s < 4; ++s)
            pvv[s] = *(const float4*)(pwb + (size_t)(s * 4 + pixo) * CC + p * 4);
#pragma unroll
        for (int s = 0; s < 4; ++s) {
            const int pix = s * 4 + pixo;
            float4 q4;
            q4.x = elu1(xv[s].x); q4.y = elu1(xv[s].y);
            q4.z = elu1(xv[s].z); q4.w = elu1(xv[s].w);
            float zp = q4.x * km4.x + q4.y * km4.y + q4.z * km4.z + q4.w * km4.w;
            zp += __shfl_xor(zp, 1);
            zp += __shfl_xor(zp, 2);
            zp += __shfl_xor(zp, 4);
            const float zin = 1.0f / (zp + 1e-6f);
            ushort4 u;
            u.x = f2bf(q4.x * pvv[s].x * zin);
            u.y = f2bf(q4.y * pvv[s].y * zin);
            u.z = f2bf(q4.z * pvv[s].z * zin);
            u.w = f2bf(q4.w * pvv[s].w * zin);
            *(ushort4*)(&qr_bf[pix * PADC + p * 4]) = u;
        }
    }
    __syncthreads();

    // ---- MFMA: wave w covers heads 2w,2w+1 over all 16 pixels ----
    {
        const int w  = t >> 6;
        const int l  = t & 63;
        const int lr = l & 15;
        const int lg = l >> 4;

        bf16x8 af0 = *(const bf16x8*)(&qr_bf[lr * PADC + (w * 2 + 0) * HD + lg * 8]);
        bf16x8 af1 = *(const bf16x8*)(&qr_bf[lr * PADC + (w * 2 + 1) * HD + lg * 8]);

        f32x4 acc[4];
#pragma unroll
        for (int ct = 0; ct < 4; ++ct) {
            const int head = w * 2 + (ct >> 1);
            const int cl   = (ct & 1) * 16 + lr;
            const bf16x8 bf = *(const bf16x8*)(kvbT +
                (((size_t)b * NHEAD + head) * HD + cl) * HD + lg * 8);
            f32x4 z4 = {0.f, 0.f, 0.f, 0.f};
            acc[ct] = __builtin_amdgcn_mfma_f32_16x16x32_bf16(
                (ct < 2) ? af0 : af1, bf, z4, 0, 0, 0);
        }
#pragma unroll
        for (int ct = 0; ct < 4; ++ct) {
            const int c = (w * 2 + (ct >> 1)) * HD + (ct & 1) * 16 + lr;
#pragma unroll
            for (int r = 0; r < 4; ++r)
                attn_bf[(lg * 4 + r) * PADC + c] = f2bf(acc[ct][r]);
        }
    }
    __syncthreads();

    // ---- coalesced bf16 attn store: lanes span consecutive channels ----
    unsigned short* ob = attn_ws + ((size_t)b * NN + (size_t)irow * 64 + j0) * CC + t;
#pragma unroll
    for (int jl = 0; jl < 16; ++jl)
        ob[(size_t)jl * CC] = attn_bf[jl * PADC + t];
}

// ---------------- k3b: out = attn + LePE — zero LDS, zero barriers --------------
// grid = B*256 (quarter image row each), block = 256. All 76 loads independent.
__global__ __launch_bounds__(256) void k3b_lepe(
    const float* __restrict__ x3, const unsigned short* __restrict__ attn_ws,
    const float* __restrict__ lw, const float* __restrict__ lb,
    float* __restrict__ out)
{
    const int blk  = blockIdx.x;      // b*256 + irow*4 + jq
    const int b    = blk >> 8;
    const int irow = (blk >> 2) & 63;
    const int jq   = blk & 3;
    const int j0   = jq << 4;
    const int t    = threadIdx.x;

    float wreg[9];
#pragma unroll
    for (int q = 0; q < 9; ++q) wreg[q] = lw[t * 9 + q];
    const float bias = lb[t];

    const bool hasU = irow > 0, hasD = irow < 63;
    const float* rU = x3 + ((size_t)b * NN + (size_t)(irow - 1) * 64 + j0) * CC + t;
    const float* rM = x3 + ((size_t)b * NN + (size_t)irow * 64 + j0) * CC + t;
    const float* rD = x3 + ((size_t)b * NN + (size_t)(irow + 1) * 64 + j0) * CC + t;
    const unsigned short* pa = attn_ws + ((size_t)b * NN + (size_t)irow * 64 + j0) * CC + t;

    // ---- attn values: 16 independent coalesced loads ----
    unsigned short av[16];
#pragma unroll
    for (int jl = 0; jl < 16; ++jl) av[jl] = pa[(size_t)jl * CC];

    // ---- halo: 60 independent loads ----
    float cu[2][10], cm[2][10], cd[2][10];
#pragma unroll
    for (int tt = 0; tt < 2; ++tt)
#pragma unroll
        for (int q = 0; q < 10; ++q) {
            const int col = tt * 8 + q - 1;
            const int g   = j0 + col;
            const bool ok = (g >= 0) && (g < 64);
            const long off = (long)col * CC;
            cm[tt][q] = ok ? rM[off] : 0.f;
            cu[tt][q] = (ok && hasU) ? rU[off] : 0.f;
            cd[tt][q] = (ok && hasD) ? rD[off] : 0.f;
        }

    float* ob = out + ((size_t)b * NN + (size_t)irow * 64 + j0) * CC + t;
#pragma unroll
    for (int tt = 0; tt < 2; ++tt) {
#pragma unroll
        for (int q = 0; q < 8; ++q) {
            const int jl = tt * 8 + q;
            float lepe = bias
                + wreg[0] * cu[tt][q] + wreg[1] * cu[tt][q + 1] + wreg[2] * cu[tt][q + 2]
                + wreg[3] * cm[tt][q] + wreg[4] * cm[tt][q + 1] + wreg[5] * cm[tt][q + 2]
                + wreg[6] * cd[tt][q] + wreg[7] * cd[tt][q + 1] + wreg[8] * cd[tt][q + 2];
            __builtin_nontemporal_store(bf2f(av[jl]) + lepe, ob + (long)jl * CC);
        }
    }
}

// ---------------- fused k3 fallback (R17 form) — used if ws too small -----------
__global__ __launch_bounds__(256) void k3_out(
    const float* __restrict__ x1, const float* __restrict__ x3,
    const float* __restrict__ pw, const unsigned short* __restrict__ kvbT,
    const float* __restrict__ kmean, const float* __restrict__ lw,
    const float* __restrict__ lb, float* __restrict__ out)
{
    const int blk  = blockIdx.x;
    const int b    = blk >> 8;
    const int irow = (blk >> 2) & 63;
    const int jq   = blk & 3;
    const int j0   = jq << 4;
    const int t    = threadIdx.x;

    __shared__ unsigned short qr_bf[16 * PADC];
    __shared__ unsigned short attn_bf[16 * PADC];

    float wreg[9];
#pragma unroll
    for (int q = 0; q < 9; ++q) wreg[q] = lw[t * 9 + q];
    const float bias = lb[t];

    {
        const int p    = t & 63;
        const int pixo = t >> 6;
        const float4 km4 = *(const float4*)(kmean + b * CC + p * 4);
        const float* x1b = x1 + ((size_t)b * NN + (size_t)irow * 64 + j0) * CC;
        const float* pwb = pw + ((size_t)irow * 64 + j0) * CC;
        float4 xv[4], pvv[4];
#pragma unroll
        for (int s = 0; s < 4; ++s)
            xv[s] = *(const float4*)(x1b + (size_t)(s * 4 + pixo) * CC + p * 4);
#pragma unroll
        for (int s = 0; s < 4; ++s)
            pvv[s] = *(const float4*)(pwb + (size_t)(s * 4 + pixo) * CC + p * 4);
#pragma unroll
        for (int s = 0; s < 4; ++s) {
            const int pix = s * 4 + pixo;
            float4 q4;
            q4.x = elu1(xv[s].x); q4.y = elu1(xv[s].y);
            q4.z = elu1(xv[s].z); q4.w = elu1(xv[s].w);
            float zp = q4.x * km4.x + q4.y * km4.y + q4.z * km4.z + q4.w * km4.w;
            zp += __shfl_xor(zp, 1);
            zp += __shfl_xor(zp, 2);
            zp += __shfl_xor(zp, 4);
            const float zin = 1.0f / (zp + 1e-6f);
            ushort4 u;
            u.x = f2bf(q4.x * pvv[s].x * zin);
            u.y = f2bf(q4.y * pvv[s].y * zin);
            u.z = f2bf(q4.z * pvv[s].z * zin);
            u.w = f2bf(q4.w * pvv[s].w * zin);
            *(ushort4*)(&qr_bf[pix * PADC + p * 4]) = u;
        }
    }

    const bool hasU = irow > 0, hasD = irow < 63;
    const float* rU = x3 + ((size_t)b * NN + (size_t)(irow - 1) * 64 + j0) * CC + t;
    const float* rM = x3 + ((size_t)b * NN + (size_t)irow * 64 + j0) * CC + t;
    const float* rD = x3 + ((size_t)b * NN + (size_t)(irow + 1) * 64 + j0) * CC + t;

    float cu[2][10], cm[2][10], cd[2][10];
#pragma unroll
    for (int tt = 0; tt < 2; ++tt)
#pragma unroll
        for (int q = 0; q < 10; ++q) {
            const int col = tt * 8 + q - 1;
            const int g   = j0 + col;
            const bool ok = (g >= 0) && (g < 64);
            const long off = (long)col * CC;
            cm[tt][q] = ok ? rM[off] : 0.f;
            cu[tt][q] = (ok && hasU) ? rU[off] : 0.f;
            cd[tt][q] = (ok && hasD) ? rD[off] : 0.f;
        }

    __syncthreads();

    {
        const int w  = t >> 6;
        const int l  = t & 63;
        const int lr = l & 15;
        const int lg = l >> 4;

        bf16x8 af0 = *(const bf16x8*)(&qr_bf[lr * PADC + (w * 2 + 0) * HD + lg * 8]);
        bf16x8 af1 = *(const bf16x8*)(&qr_bf[lr * PADC + (w * 2 + 1) * HD + lg * 8]);

        f32x4 acc[4];
#pragma unroll
        for (int ct = 0; ct < 4; ++ct) {
            const int head = w * 2 + (ct >> 1);
            const int cl   = (ct & 1) * 16 + lr;
            const bf16x8 bf = *(const bf16x8*)(kvbT +
                (((size_t)b * NHEAD + head) * HD + cl) * HD + lg * 8);
            f32x4 z4 = {0.f, 0.f, 0.f, 0.f};
            acc[ct] = __builtin_amdgcn_mfma_f32_16x16x32_bf16(
                (ct < 2) ? af0 : af1, bf, z4, 0, 0, 0);
        }
#pragma unroll
        for (int ct = 0; ct < 4; ++ct) {
            const int c = (w * 2 + (ct >> 1)) * HD + (ct & 1) * 16 + lr;
#pragma unroll
            for (int r = 0; r < 4; ++r)
                attn_bf[(lg * 4 + r) * PADC + c] = f2bf(acc[ct][r]);
        }
    }

    __syncthreads();

    float* ob = out + ((size_t)b * NN + (size_t)irow * 64 + j0) * CC + t;
#pragma unroll
    for (int tt = 0; tt < 2; ++tt) {
#pragma unroll
        for (int q = 0; q < 8; ++q) {
            const int jl = tt * 8 + q;
            float lepe = bias
                + wreg[0] * cu[tt][q] + wreg[1] * cu[tt][q + 1] + wreg[2] * cu[tt][q + 2]
                + wreg[3] * cm[tt][q] + wreg[4] * cm[tt][q + 1] + wreg[5] * cm[tt][q + 2]
                + wreg[6] * cd[tt][q] + wreg[7] * cd[tt][q + 1] + wreg[8] * cd[tt][q + 2];
            __builtin_nontemporal_store(bf2f(attn_bf[jl * PADC + t]) + lepe,
                                        ob + (long)jl * CC);
        }
    }
}

extern "C" void kernel_launch(void* const* d_in, const int* in_sizes, int n_in,
                              void* d_out, int out_size, void* d_ws, size_t ws_size,
                              hipStream_t stream) {
    const float* x1   = (const float*)d_in[0];
    const float* x2   = (const float*)d_in[1];
    const float* x3   = (const float*)d_in[2];
    const float* posw = (const float*)d_in[3];
    const float* lw   = (const float*)d_in[4];
    const float* lb   = (const float*)d_in[5];
    float* out = (float*)d_out;

    // ws layout (floats unless noted): pw | pkv | pksum | kmean | kvbT(u16) | attn(u16)
    const size_t pw_f  = (size_t)NN * CC;            // 1M
    const size_t pkv_f = (size_t)16 * NCH * 8192;    // 4.19M
    const size_t pks_f = (size_t)16 * NCH * 256;     // 131K
    const size_t km_f  = (size_t)16 * 256;           // 4K
    const size_t kvbT_u = (size_t)16 * 8192;         // ushorts
    const size_t attn_u = (size_t)16 * NN * CC;      // ushorts (32 MB)

    float* pwb   = (float*)d_ws;
    float* pkv   = pwb + pw_f;
    float* pksum = pkv + pkv_f;
    float* kmean = pksum + pks_f;
    unsigned short* kvbT = (unsigned short*)(kmean + km_f);
    unsigned short* attn_ws = kvbT + kvbT_u;

    const size_t need_split = (pw_f + pkv_f + pks_f + km_f) * sizeof(float) +
                              (kvbT_u + attn_u) * sizeof(unsigned short);

    k0_pw<<<1024, 256, 0, stream>>>(posw, pwb);
    k1_partial<<<BB * NCH, 256, 0, stream>>>(x2, x3, pwb, pkv, pksum);
    k2_reduce<<<512, 256, 0, stream>>>(pkv, pksum, kvbT, kmean);
    if (ws_size >= need_split) {
        k3a_attn<<<BB * 256, 256, 0, stream>>>(x1, pwb, kvbT, kmean, attn_ws);
        k3b_lepe<<<BB * 256, 256, 0, stream>>>(x3, attn_ws, lw, lb, out);
    } else {
        k3_out<<<BB * 256, 256, 0, stream>>>(x1, x3, pwb, kvbT, kmean, lw, lb, out);
    }
}

// Round 20
// 93.529 us; speedup vs baseline: 1.0093x; 1.0093x over previous
//
#include <hip/hip_runtime.h>

#define BB 16
#define HIMG 64
#define WIMG 64
#define CC 256
#define NHEAD 8
#define HD 32
#define NN 4096
#define PWD 65   // 2*DH+1
#define PADC 264 // qr_bf / attn_bf row stride (ushorts)

typedef short bf16x8 __attribute__((ext_vector_type(8)));
typedef float f32x4 __attribute__((ext_vector_type(4)));

__device__ __forceinline__ float elu1(float x) {
    return x > 0.0f ? x + 1.0f : __expf(x);
}
__device__ __forceinline__ float sigm(float x) {
    return 1.0f / (1.0f + __expf(-x));
}
__device__ __forceinline__ unsigned short f2bf(float f) {
    union { float f; unsigned int u; } v; v.f = f;
    unsigned int r = v.u + 0x7FFFu + ((v.u >> 16) & 1u);   // RNE
    return (unsigned short)(r >> 16);
}
__device__ __forceinline__ float bf2f(unsigned short u) {
    union { unsigned int u; float f; } v; v.u = ((unsigned int)u) << 16;
    return v.f;
}

// ---------------- Kernel 0: pw[n][c] = sigmoid(posw[i+1][j+1][c]) ---------------
__global__ __launch_bounds__(256) void k0_pw(
    const float* __restrict__ posw, float* __restrict__ pw)
{
    const int gid = blockIdx.x * 256 + threadIdx.x;  // 0 .. 262143
    const int n = gid >> 6;
    const int p = gid & 63;
    const int ii = n >> 6, jj = n & 63;
    const float4 v = *(const float4*)(posw + (size_t)((ii + 1) * PWD + (jj + 1)) * CC + p * 4);
    float4 r;
    r.x = sigm(v.x); r.y = sigm(v.y); r.z = sigm(v.z); r.w = sigm(v.w);
    *(float4*)(pw + (size_t)n * CC + p * 4) = r;
}

// ---------------- Kernel 1: partial kv — no LDS, no barriers, fragment loads ----
// grid = 16*nch (b x chunk), block = 256 (4 waves). Wave wv -> heads {2wv,2wv+1}.
// nch=64 (64-row chunks) -> 1024 blocks = 4 blocks/CU = 16 waves/CU (2x R16 TLP).
// Lane l loads A/B fragments DIRECTLY from global in MFMA lane order.
// Per 32-row subtile per wave: 96 independent loads, elu*pw -> bf16 pack,
// 8x mfma_16x16x32_bf16. ksum per-lane + shfl_xor. Zero LDS. Zero barriers.
__global__ __launch_bounds__(256) void k1_partial(
    const float* __restrict__ x2, const float* __restrict__ x3,
    const float* __restrict__ pw, float* __restrict__ pkv,
    float* __restrict__ pksum, int nchl, int nsub)
{
    const int t     = threadIdx.x;
    const int wv    = t >> 6;              // 0..3 -> heads 2wv, 2wv+1
    const int blk   = blockIdx.x;          // b*nch + chunk
    const int b     = blk >> nchl;
    const int chunk = blk & ((1 << nchl) - 1);
    const int l     = t & 63;
    const int lr    = l & 15;              // fragment row/col within 16
    const int lg    = l >> 4;              // k-group: rows lg*8 + j

    const size_t bb = (size_t)b * NN * CC;

    f32x4 acc[2][4];
#pragma unroll
    for (int hh = 0; hh < 2; ++hh)
#pragma unroll
        for (int tl = 0; tl < 4; ++tl)
            acc[hh][tl] = (f32x4){0.f, 0.f, 0.f, 0.f};
    float ks[2][2] = {{0.f, 0.f}, {0.f, 0.f}};

    for (int s = 0; s < nsub; ++s) {
        const int n0 = chunk * (nsub * 32) + s * 32 + lg * 8;   // lane's row base

        float kf[2][2][8], pf[2][2][8], vf[2][2][8];
        // ---- all 96 loads issued up-front, fully independent ----
#pragma unroll
        for (int hh = 0; hh < 2; ++hh)
#pragma unroll
            for (int dh = 0; dh < 2; ++dh) {
                const int ch = (wv * 2 + hh) * HD + dh * 16 + lr;
                const float* pk = x2 + bb + (size_t)n0 * CC + ch;
#pragma unroll
                for (int j = 0; j < 8; ++j) kf[hh][dh][j] = pk[j * CC];
            }
#pragma unroll
        for (int hh = 0; hh < 2; ++hh)
#pragma unroll
            for (int dh = 0; dh < 2; ++dh) {
                const int ch = (wv * 2 + hh) * HD + dh * 16 + lr;
                const float* pp = pw + (size_t)n0 * CC + ch;
#pragma unroll
                for (int j = 0; j < 8; ++j) pf[hh][dh][j] = pp[j * CC];
            }
#pragma unroll
        for (int hh = 0; hh < 2; ++hh)
#pragma unroll
            for (int eh = 0; eh < 2; ++eh) {
                const int ch = (wv * 2 + hh) * HD + eh * 16 + lr;
                const float* pv = x3 + bb + (size_t)n0 * CC + ch;
#pragma unroll
                for (int j = 0; j < 8; ++j) vf[hh][eh][j] = pv[j * CC];
            }

        // ---- transform + MFMA ----
#pragma unroll
        for (int hh = 0; hh < 2; ++hh) {
            union { bf16x8 v8; unsigned short u[8]; } ka[2], vb[2];
#pragma unroll
            for (int dh = 0; dh < 2; ++dh)
#pragma unroll
                for (int j = 0; j < 8; ++j) {
                    const float e = elu1(kf[hh][dh][j]);
                    ks[hh][dh] += e;
                    ka[dh].u[j] = f2bf(e * pf[hh][dh][j]);
                }
#pragma unroll
            for (int eh = 0; eh < 2; ++eh)
#pragma unroll
                for (int j = 0; j < 8; ++j)
                    vb[eh].u[j] = f2bf(vf[hh][eh][j]);
#pragma unroll
            for (int dh = 0; dh < 2; ++dh)
#pragma unroll
                for (int eh = 0; eh < 2; ++eh)
                    acc[hh][dh * 2 + eh] = __builtin_amdgcn_mfma_f32_16x16x32_bf16(
                        ka[dh].v8, vb[eh].v8, acc[hh][dh * 2 + eh], 0, 0, 0);
        }
    }

    // ---- store kv partials, MFMA-native layout (R12-verified k2 decode) ----
#pragma unroll
    for (int hh = 0; hh < 2; ++hh) {
        float* dst = pkv + (size_t)blk * (NHEAD * HD * HD) + (wv * 2 + hh) * (HD * HD);
#pragma unroll
        for (int tl = 0; tl < 4; ++tl)
            *(f32x4*)(dst + tl * 256 + l * 4) = acc[hh][tl];
    }

    // ---- ksum: reduce over lg (lane bits 4,5); lanes 0..15 hold channel sums ----
#pragma unroll
    for (int hh = 0; hh < 2; ++hh)
#pragma unroll
        for (int dh = 0; dh < 2; ++dh) {
            ks[hh][dh] += __shfl_xor(ks[hh][dh], 16);
            ks[hh][dh] += __shfl_xor(ks[hh][dh], 32);
        }
    if (l < 16) {
#pragma unroll
        for (int hh = 0; hh < 2; ++hh)
#pragma unroll
            for (int dh = 0; dh < 2; ++dh)
                pksum[(size_t)blk * CC + (wv * 2 + hh) * HD + dh * 16 + l] = ks[hh][dh];
    }
}

// ---------------- Kernel 2: reduce partials; emit kvbT (bf16, [b][h][e][d]) -----
// grid = 512, block = 256. pkv o-layout MFMA-native: h*1024 + tile*256 + l*4 + r.
__global__ __launch_bounds__(256) void k2_reduce(
    const float* __restrict__ pkv, const float* __restrict__ pksum,
    unsigned short* __restrict__ kvbT, float* __restrict__ kmean, int nch)
{
    const int gid = blockIdx.x * 256 + threadIdx.x;   // over B*8192
    const int b = gid >> 13;
    const int o = gid & 8191;
    float s = 0.f;
#pragma unroll 4
    for (int c = 0; c < nch; ++c)
        s += pkv[(size_t)(b * nch + c) * (NHEAD * HD * HD) + o];
    const int hh   = o >> 10;
    const int r1   = o & 1023;
    const int tile = r1 >> 8;
    const int li   = (r1 >> 2) & 63;
    const int rg   = o & 3;
    const int d    = (tile >> 1) * 16 + (li >> 4) * 4 + rg;
    const int e    = (tile & 1) * 16 + (li & 15);
    kvbT[(((size_t)b * NHEAD + hh) * HD + e) * HD + d] = f2bf(s * (1.0f / NN));
    if (o < CC) {
        float ss = 0.f;
#pragma unroll 4
        for (int c = 0; c < nch; ++c)
            ss += pksum[(size_t)(b * nch + c) * CC + o];
        kmean[b * CC + o] = ss * (1.0f / NN);
    }
}

// ---------------- Kernel 3: out = MFMA((qr*z) @ kv) + LePE (R16 form) -----------
// grid = B*256 (quarter image row each), block = 256 (4 waves).
__global__ __launch_bounds__(256) void k3_out(
    const float* __restrict__ x1, const float* __restrict__ x3,
    const float* __restrict__ pw, const unsigned short* __restrict__ kvbT,
    const float* __restrict__ kmean, const float* __restrict__ lw,
    const float* __restrict__ lb, float* __restrict__ out)
{
    const int blk  = blockIdx.x;      // b*256 + irow*4 + jq
    const int b    = blk >> 8;
    const int irow = (blk >> 2) & 63;
    const int jq   = blk & 3;
    const int j0   = jq << 4;         // 0, 16, 32, 48
    const int t    = threadIdx.x;

    __shared__ unsigned short qr_bf[16 * PADC];    // (qr*z) bf16, 8.4 KiB
    __shared__ unsigned short attn_bf[16 * PADC];  // attn bf16,   8.4 KiB

    float wreg[9];
#pragma unroll
    for (int q = 0; q < 9; ++q) wreg[q] = lw[t * 9 + q];
    const float bias = lb[t];

    // ---- stage: q_rope * z  -> bf16 LDS (z folded in; known after shfl reduce) ----
    {
        const int p    = t & 63;       // float4 slot within a pixel's 256 channels
        const int pixo = t >> 6;       // 0..3
        const float4 km4 = *(const float4*)(kmean + b * CC + p * 4);
        const float* x1b = x1 + ((size_t)b * NN + (size_t)irow * 64 + j0) * CC;
        const float* pwb = pw + ((size_t)irow * 64 + j0) * CC;
        float4 xv[4], pvv[4];
#pragma unroll
        for (int s = 0; s < 4; ++s)
            xv[s] = *(const float4*)(x1b + (size_t)(s * 4 + pixo) * CC + p * 4);
#pragma unroll
        for (int s = 0; s < 4; ++s)
            pvv[s] = *(const float4*)(pwb + (size_t)(s * 4 + pixo) * CC + p * 4);
#pragma unroll
        for (int s = 0; s < 4; ++s) {
            const int pix = s * 4 + pixo;   // 0..15 (local)
            float4 q4;
            q4.x = elu1(xv[s].x); q4.y = elu1(xv[s].y);
            q4.z = elu1(xv[s].z); q4.w = elu1(xv[s].w);
            float zp = q4.x * km4.x + q4.y * km4.y + q4.z * km4.z + q4.w * km4.w;
            zp += __shfl_xor(zp, 1);
            zp += __shfl_xor(zp, 2);
            zp += __shfl_xor(zp, 4);        // all 8 lanes of this head have the sum
            const float zin = 1.0f / (zp + 1e-6f);
            ushort4 u;
            u.x = f2bf(q4.x * pvv[s].x * zin);
            u.y = f2bf(q4.y * pvv[s].y * zin);
            u.z = f2bf(q4.z * pvv[s].z * zin);
            u.w = f2bf(q4.w * pvv[s].w * zin);
            *(ushort4*)(&qr_bf[pix * PADC + p * 4]) = u;
        }
    }

    // ---- halo loads issued BEFORE the barrier: cannot be sunk past it ----
    const bool hasU = irow > 0, hasD = irow < 63;
    const float* rU = x3 + ((size_t)b * NN + (size_t)(irow - 1) * 64 + j0) * CC + t;
    const float* rM = x3 + ((size_t)b * NN + (size_t)irow * 64 + j0) * CC + t;
    const float* rD = x3 + ((size_t)b * NN + (size_t)(irow + 1) * 64 + j0) * CC + t;

    float cu[2][10], cm[2][10], cd[2][10];
#pragma unroll
    for (int tt = 0; tt < 2; ++tt)
#pragma unroll
        for (int q = 0; q < 10; ++q) {
            const int col = tt * 8 + q - 1;     // local col in [-1, 16]
            const int g   = j0 + col;           // global col in [-1, 64]
            const bool ok = (g >= 0) && (g < 64);
            const long off = (long)col * CC;
            cm[tt][q] = ok ? rM[off] : 0.f;
            cu[tt][q] = (ok && hasU) ? rU[off] : 0.f;
            cd[tt][q] = (ok && hasD) ? rD[off] : 0.f;
        }

    __syncthreads();

    // ---- MFMA phase: wave w covers heads 2w,2w+1 over all 16 pixels ----
    {
        const int w  = t >> 6;
        const int l  = t & 63;
        const int lr = l & 15;     // A row (pixel) / B col / D col
        const int lg = l >> 4;     // k-group

        bf16x8 af0 = *(const bf16x8*)(&qr_bf[lr * PADC + (w * 2 + 0) * HD + lg * 8]);
        bf16x8 af1 = *(const bf16x8*)(&qr_bf[lr * PADC + (w * 2 + 1) * HD + lg * 8]);

        f32x4 acc[4];
#pragma unroll
        for (int ct = 0; ct < 4; ++ct) {
            const int head = w * 2 + (ct >> 1);
            const int cl   = (ct & 1) * 16 + lr;
            const bf16x8 bf = *(const bf16x8*)(kvbT +
                (((size_t)b * NHEAD + head) * HD + cl) * HD + lg * 8);
            f32x4 z4 = {0.f, 0.f, 0.f, 0.f};
            acc[ct] = __builtin_amdgcn_mfma_f32_16x16x32_bf16(
                (ct < 2) ? af0 : af1, bf, z4, 0, 0, 0);
        }
#pragma unroll
        for (int ct = 0; ct < 4; ++ct) {
            const int c = (w * 2 + (ct >> 1)) * HD + (ct & 1) * 16 + lr;
#pragma unroll
            for (int r = 0; r < 4; ++r)
                attn_bf[(lg * 4 + r) * PADC + c] = f2bf(acc[ct][r]);
        }
    }

    __syncthreads();

    // ---- epilogue: lepe (registers already loaded) + attn + store ----
    float* ob = out + ((size_t)b * NN + (size_t)irow * 64 + j0) * CC + t;
#pragma unroll
    for (int tt = 0; tt < 2; ++tt) {
#pragma unroll
        for (int q = 0; q < 8; ++q) {
            const int jl = tt * 8 + q;          // local pixel 0..15
            float lepe = bias
                + wreg[0] * cu[tt][q] + wreg[1] * cu[tt][q + 1] + wreg[2] * cu[tt][q + 2]
                + wreg[3] * cm[tt][q] + wreg[4] * cm[tt][q + 1] + wreg[5] * cm[tt][q + 2]
                + wreg[6] * cd[tt][q] + wreg[7] * cd[tt][q + 1] + wreg[8] * cd[tt][q + 2];
            __builtin_nontemporal_store(bf2f(attn_bf[jl * PADC + t]) + lepe,
                                        ob + (long)jl * CC);
        }
    }
}

extern "C" void kernel_launch(void* const* d_in, const int* in_sizes, int n_in,
                              void* d_out, int out_size, void* d_ws, size_t ws_size,
                              hipStream_t stream) {
    const float* x1   = (const float*)d_in[0];
    const float* x2   = (const float*)d_in[1];
    const float* x3   = (const float*)d_in[2];
    const float* posw = (const float*)d_in[3];
    const float* lw   = (const float*)d_in[4];
    const float* lb   = (const float*)d_in[5];
    float* out = (float*)d_out;

    // choose nch by workspace: nch=64 needs ~38.4 MB, else nch=32 (R16 behavior)
    const size_t pw_f  = (size_t)NN * CC;
    const size_t need64 = (pw_f + (size_t)16 * 64 * 8192 + (size_t)16 * 64 * 256 +
                           (size_t)16 * 256) * sizeof(float) +
                          (size_t)16 * 8192 * sizeof(unsigned short);
    const int nchl = (ws_size >= need64) ? 6 : 5;
    const int nch  = 1 << nchl;
    const int nsub = 128 >> nchl;          // 32-row subtiles per chunk: 2 or 4

    float* pwb   = (float*)d_ws;
    float* pkv   = pwb + pw_f;                              // 16*nch * 8192
    float* pksum = pkv + (size_t)16 * nch * 8192;           // 16*nch * 256
    float* kmean = pksum + (size_t)16 * nch * 256;          // 16 * 256
    unsigned short* kvbT = (unsigned short*)(kmean + (size_t)16 * 256);  // 16*8192

    k0_pw<<<1024, 256, 0, stream>>>(posw, pwb);
    k1_partial<<<16 * nch, 256, 0, stream>>>(x2, x3, pwb, pkv, pksum, nchl, nsub);
    k2_reduce<<<512, 256, 0, stream>>>(pkv, pksum, kvbT, kmean, nch);
    k3_out<<<BB * 256, 256, 0, stream>>>(x1, x3, pwb, kvbT, kmean, lw, lb, out);
}

// Round 21
// 81.996 us; speedup vs baseline: 1.1513x; 1.1407x over previous
//
#include <hip/hip_runtime.h>

#define BB 16
#define HIMG 64
#define WIMG 64
#define CC 256
#define NHEAD 8
#define HD 32
#define NN 4096
#define PWD 65   // 2*DH+1
#define PADC 264 // qr_bf / attn_bf row stride (ushorts)
#define NCH 32   // k1 chunks per batch (128 rows each)

typedef short bf16x8 __attribute__((ext_vector_type(8)));
typedef float f32x4 __attribute__((ext_vector_type(4)));

__device__ __forceinline__ float elu1(float x) {
    return x > 0.0f ? x + 1.0f : __expf(x);
}
__device__ __forceinline__ float sigm(float x) {
    return 1.0f / (1.0f + __expf(-x));
}
__device__ __forceinline__ unsigned short f2bf(float f) {
    union { float f; unsigned int u; } v; v.f = f;
    unsigned int r = v.u + 0x7FFFu + ((v.u >> 16) & 1u);   // RNE
    return (unsigned short)(r >> 16);
}
__device__ __forceinline__ float bf2f(unsigned short u) {
    union { unsigned int u; float f; } v; v.u = ((unsigned int)u) << 16;
    return v.f;
}

// ---------------- Kernel 0: pw[n][c] = sigmoid(posw[i+1][j+1][c]) ---------------
__global__ __launch_bounds__(256) void k0_pw(
    const float* __restrict__ posw, float* __restrict__ pw)
{
    const int gid = blockIdx.x * 256 + threadIdx.x;  // 0 .. 262143
    const int n = gid >> 6;
    const int p = gid & 63;
    const int ii = n >> 6, jj = n & 63;
    const float4 v = *(const float4*)(posw + (size_t)((ii + 1) * PWD + (jj + 1)) * CC + p * 4);
    float4 r;
    r.x = sigm(v.x); r.y = sigm(v.y); r.z = sigm(v.z); r.w = sigm(v.w);
    *(float4*)(pw + (size_t)n * CC + p * 4) = r;
}

// ---------------- Kernel 1: partial kv — no LDS, no barriers, fragment loads ----
// grid = 512 (b x chunk128), block = 256 (4 waves). Wave wv -> heads {2wv,2wv+1}.
// Lane l loads A/B fragments DIRECTLY from global in MFMA lane order.
// Per 32-row subtile per wave: 96 independent loads, elu*pw -> bf16 pack,
// 8x mfma_16x16x32_bf16. ksum per-lane + shfl_xor. Zero LDS. Zero barriers.
__global__ __launch_bounds__(256) void k1_partial(
    const float* __restrict__ x2, const float* __restrict__ x3,
    const float* __restrict__ pw, float* __restrict__ pkv,
    float* __restrict__ pksum)
{
    const int t     = threadIdx.x;
    const int wv    = t >> 6;              // 0..3 -> heads 2wv, 2wv+1
    const int blk   = blockIdx.x;          // b*NCH + chunk
    const int b     = blk >> 5;
    const int chunk = blk & 31;
    const int l     = t & 63;
    const int lr    = l & 15;              // fragment row/col within 16
    const int lg    = l >> 4;              // k-group: rows lg*8 + j

    const size_t bb = (size_t)b * NN * CC;

    f32x4 acc[2][4];
#pragma unroll
    for (int hh = 0; hh < 2; ++hh)
#pragma unroll
        for (int tl = 0; tl < 4; ++tl)
            acc[hh][tl] = (f32x4){0.f, 0.f, 0.f, 0.f};
    float ks[2][2] = {{0.f, 0.f}, {0.f, 0.f}};

    for (int s = 0; s < 4; ++s) {
        const int n0 = chunk * 128 + s * 32 + lg * 8;   // this lane's row base

        float kf[2][2][8], pf[2][2][8], vf[2][2][8];
        // ---- all 96 loads issued up-front, fully independent ----
#pragma unroll
        for (int hh = 0; hh < 2; ++hh)
#pragma unroll
            for (int dh = 0; dh < 2; ++dh) {
                const int ch = (wv * 2 + hh) * HD + dh * 16 + lr;
                const float* pk = x2 + bb + (size_t)n0 * CC + ch;
#pragma unroll
                for (int j = 0; j < 8; ++j) kf[hh][dh][j] = pk[j * CC];
            }
#pragma unroll
        for (int hh = 0; hh < 2; ++hh)
#pragma unroll
            for (int dh = 0; dh < 2; ++dh) {
                const int ch = (wv * 2 + hh) * HD + dh * 16 + lr;
                const float* pp = pw + (size_t)n0 * CC + ch;
#pragma unroll
                for (int j = 0; j < 8; ++j) pf[hh][dh][j] = pp[j * CC];
            }
#pragma unroll
        for (int hh = 0; hh < 2; ++hh)
#pragma unroll
            for (int eh = 0; eh < 2; ++eh) {
                const int ch = (wv * 2 + hh) * HD + eh * 16 + lr;
                const float* pv = x3 + bb + (size_t)n0 * CC + ch;
#pragma unroll
                for (int j = 0; j < 8; ++j) vf[hh][eh][j] = pv[j * CC];
            }

        // ---- transform + MFMA ----
#pragma unroll
        for (int hh = 0; hh < 2; ++hh) {
            union { bf16x8 v8; unsigned short u[8]; } ka[2], vb[2];
#pragma unroll
            for (int dh = 0; dh < 2; ++dh)
#pragma unroll
                for (int j = 0; j < 8; ++j) {
                    const float e = elu1(kf[hh][dh][j]);
                    ks[hh][dh] += e;
                    ka[dh].u[j] = f2bf(e * pf[hh][dh][j]);
                }
#pragma unroll
            for (int eh = 0; eh < 2; ++eh)
#pragma unroll
                for (int j = 0; j < 8; ++j)
                    vb[eh].u[j] = f2bf(vf[hh][eh][j]);
#pragma unroll
            for (int dh = 0; dh < 2; ++dh)
#pragma unroll
                for (int eh = 0; eh < 2; ++eh)
                    acc[hh][dh * 2 + eh] = __builtin_amdgcn_mfma_f32_16x16x32_bf16(
                        ka[dh].v8, vb[eh].v8, acc[hh][dh * 2 + eh], 0, 0, 0);
        }
    }

    // ---- store kv partials, MFMA-native layout (R12-verified k2 decode) ----
#pragma unroll
    for (int hh = 0; hh < 2; ++hh) {
        float* dst = pkv + (size_t)blk * (NHEAD * HD * HD) + (wv * 2 + hh) * (HD * HD);
#pragma unroll
        for (int tl = 0; tl < 4; ++tl)
            *(f32x4*)(dst + tl * 256 + l * 4) = acc[hh][tl];
    }

    // ---- ksum: reduce over lg (lane bits 4,5); lanes 0..15 hold channel sums ----
#pragma unroll
    for (int hh = 0; hh < 2; ++hh)
#pragma unroll
        for (int dh = 0; dh < 2; ++dh) {
            ks[hh][dh] += __shfl_xor(ks[hh][dh], 16);
            ks[hh][dh] += __shfl_xor(ks[hh][dh], 32);
        }
    if (l < 16) {
#pragma unroll
        for (int hh = 0; hh < 2; ++hh)
#pragma unroll
            for (int dh = 0; dh < 2; ++dh)
                pksum[(size_t)blk * CC + (wv * 2 + hh) * HD + dh * 16 + l] = ks[hh][dh];
    }
}

// ---------------- Kernel 2: reduce partials; emit kvbT (bf16, [b][h][e][d]) -----
// grid = 512, block = 256. pkv o-layout MFMA-native: h*1024 + tile*256 + l*4 + r,
// tile = dt*2+et (verified correct in R12: absmax 0.0078).
__global__ __launch_bounds__(256) void k2_reduce(
    const float* __restrict__ pkv, const float* __restrict__ pksum,
    unsigned short* __restrict__ kvbT, float* __restrict__ kmean)
{
    const int gid = blockIdx.x * 256 + threadIdx.x;   // over B*8192
    const int b = gid >> 13;
    const int o = gid & 8191;
    float s = 0.f;
#pragma unroll 4
    for (int c = 0; c < NCH; ++c)
        s += pkv[(size_t)(b * NCH + c) * (NHEAD * HD * HD) + o];
    const int hh   = o >> 10;
    const int r1   = o & 1023;
    const int tile = r1 >> 8;
    const int li   = (r1 >> 2) & 63;
    const int rg   = o & 3;
    const int d    = (tile >> 1) * 16 + (li >> 4) * 4 + rg;
    const int e    = (tile & 1) * 16 + (li & 15);
    kvbT[(((size_t)b * NHEAD + hh) * HD + e) * HD + d] = f2bf(s * (1.0f / NN));
    if (o < CC) {
        float ss = 0.f;
#pragma unroll 4
        for (int c = 0; c < NCH; ++c)
            ss += pksum[(size_t)(b * NCH + c) * CC + o];
        kmean[b * CC + o] = ss * (1.0f / NN);
    }
}

// ---------------- Kernel 3: out = MFMA((qr*z) @ kv) + LePE ----------------------
// grid = B*256 (quarter image row each), block = 256 (4 waves).
// LDS 16.9 KiB (attn staged in bf16); plain launch bounds (no VGPR strangling).
__global__ __launch_bounds__(256) void k3_out(
    const float* __restrict__ x1, const float* __restrict__ x3,
    const float* __restrict__ pw, const unsigned short* __restrict__ kvbT,
    const float* __restrict__ kmean, const float* __restrict__ lw,
    const float* __restrict__ lb, float* __restrict__ out)
{
    const int blk  = blockIdx.x;      // b*256 + irow*4 + jq
    const int b    = blk >> 8;
    const int irow = (blk >> 2) & 63;
    const int jq   = blk & 3;
    const int j0   = jq << 4;         // 0, 16, 32, 48
    const int t    = threadIdx.x;

    __shared__ unsigned short qr_bf[16 * PADC];    // (qr*z) bf16, 8.4 KiB
    __shared__ unsigned short attn_bf[16 * PADC];  // attn bf16,   8.4 KiB

    float wreg[9];
#pragma unroll
    for (int q = 0; q < 9; ++q) wreg[q] = lw[t * 9 + q];
    const float bias = lb[t];

    // ---- stage: q_rope * z  -> bf16 LDS (z folded in; known after shfl reduce) ----
    {
        const int p    = t & 63;       // float4 slot within a pixel's 256 channels
        const int pixo = t >> 6;       // 0..3
        const float4 km4 = *(const float4*)(kmean + b * CC + p * 4);
        const float* x1b = x1 + ((size_t)b * NN + (size_t)irow * 64 + j0) * CC;
        const float* pwb = pw + ((size_t)irow * 64 + j0) * CC;
        float4 xv[4], pvv[4];
#pragma unroll
        for (int s = 0; s < 4; ++s)
            xv[s] = *(const float4*)(x1b + (size_t)(s * 4 + pixo) * CC + p * 4);
#pragma unroll
        for (int s = 0; s < 4; ++s)
            pvv[s] = *(const float4*)(pwb + (size_t)(s * 4 + pixo) * CC + p * 4);
#pragma unroll
        for (int s = 0; s < 4; ++s) {
            const int pix = s * 4 + pixo;   // 0..15 (local)
            float4 q4;
            q4.x = elu1(xv[s].x); q4.y = elu1(xv[s].y);
            q4.z = elu1(xv[s].z); q4.w = elu1(xv[s].w);
            float zp = q4.x * km4.x + q4.y * km4.y + q4.z * km4.z + q4.w * km4.w;
            zp += __shfl_xor(zp, 1);
            zp += __shfl_xor(zp, 2);
            zp += __shfl_xor(zp, 4);        // all 8 lanes of this head have the sum
            const float zin = 1.0f / (zp + 1e-6f);
            ushort4 u;
            u.x = f2bf(q4.x * pvv[s].x * zin);
            u.y = f2bf(q4.y * pvv[s].y * zin);
            u.z = f2bf(q4.z * pvv[s].z * zin);
            u.w = f2bf(q4.w * pvv[s].w * zin);
            *(ushort4*)(&qr_bf[pix * PADC + p * 4]) = u;
        }
    }

    // ---- halo loads issued BEFORE the barrier: cannot be sunk past it ----
    const bool hasU = irow > 0, hasD = irow < 63;
    const float* rU = x3 + ((size_t)b * NN + (size_t)(irow - 1) * 64 + j0) * CC + t;
    const float* rM = x3 + ((size_t)b * NN + (size_t)irow * 64 + j0) * CC + t;
    const float* rD = x3 + ((size_t)b * NN + (size_t)(irow + 1) * 64 + j0) * CC + t;

    float cu[2][10], cm[2][10], cd[2][10];
#pragma unroll
    for (int tt = 0; tt < 2; ++tt)
#pragma unroll
        for (int q = 0; q < 10; ++q) {
            const int col = tt * 8 + q - 1;     // local col in [-1, 16]
            const int g   = j0 + col;           // global col in [-1, 64]
            const bool ok = (g >= 0) && (g < 64);
            const long off = (long)col * CC;
            cm[tt][q] = ok ? rM[off] : 0.f;
            cu[tt][q] = (ok && hasU) ? rU[off] : 0.f;
            cd[tt][q] = (ok && hasD) ? rD[off] : 0.f;
        }

    __syncthreads();

    // ---- MFMA phase: wave w covers heads 2w,2w+1 over all 16 pixels ----
    {
        const int w  = t >> 6;
        const int l  = t & 63;
        const int lr = l & 15;     // A row (pixel) / B col / D col
        const int lg = l >> 4;     // k-group

        bf16x8 af0 = *(const bf16x8*)(&qr_bf[lr * PADC + (w * 2 + 0) * HD + lg * 8]);
        bf16x8 af1 = *(const bf16x8*)(&qr_bf[lr * PADC + (w * 2 + 1) * HD + lg * 8]);

        f32x4 acc[4];
#pragma unroll
        for (int ct = 0; ct < 4; ++ct) {
            const int head = w * 2 + (ct >> 1);
            const int cl   = (ct & 1) * 16 + lr;
            const bf16x8 bf = *(const bf16x8*)(kvbT +
                (((size_t)b * NHEAD + head) * HD + cl) * HD + lg * 8);
            f32x4 z4 = {0.f, 0.f, 0.f, 0.f};
            acc[ct] = __builtin_amdgcn_mfma_f32_16x16x32_bf16(
                (ct < 2) ? af0 : af1, bf, z4, 0, 0, 0);
        }
#pragma unroll
        for (int ct = 0; ct < 4; ++ct) {
            const int c = (w * 2 + (ct >> 1)) * HD + (ct & 1) * 16 + lr;
#pragma unroll
            for (int r = 0; r < 4; ++r)
                attn_bf[(lg * 4 + r) * PADC + c] = f2bf(acc[ct][r]);
        }
    }

    __syncthreads();

    // ---- epilogue: lepe (registers already loaded) + attn + store ----
    float* ob = out + ((size_t)b * NN + (size_t)irow * 64 + j0) * CC + t;
#pragma unroll
    for (int tt = 0; tt < 2; ++tt) {
#pragma unroll
        for (int q = 0; q < 8; ++q) {
            const int jl = tt * 8 + q;          // local pixel 0..15
            float lepe = bias
                + wreg[0] * cu[tt][q] + wreg[1] * cu[tt][q + 1] + wreg[2] * cu[tt][q + 2]
                + wreg[3] * cm[tt][q] + wreg[4] * cm[tt][q + 1] + wreg[5] * cm[tt][q + 2]
                + wreg[6] * cd[tt][q] + wreg[7] * cd[tt][q + 1] + wreg[8] * cd[tt][q + 2];
            __builtin_nontemporal_store(bf2f(attn_bf[jl * PADC + t]) + lepe,
                                        ob + (long)jl * CC);
        }
    }
}

extern "C" void kernel_launch(void* const* d_in, const int* in_sizes, int n_in,
                              void* d_out, int out_size, void* d_ws, size_t ws_size,
                              hipStream_t stream) {
    const float* x1   = (const float*)d_in[0];
    const float* x2   = (const float*)d_in[1];
    const float* x3   = (const float*)d_in[2];
    const float* posw = (const float*)d_in[3];
    const float* lw   = (const float*)d_in[4];
    const float* lb   = (const float*)d_in[5];
    float* out = (float*)d_out;

    // ws layout: pw | pkv | pksum | kmean | kvbT(ushort)  (~21.6 MB)
    const size_t pw_sz = (size_t)NN * CC;                   // 1M floats
    float* pwb   = (float*)d_ws;
    float* pkv   = pwb + pw_sz;                             // 16*NCH * 8192
    float* pksum = pkv + (size_t)16 * NCH * 8192;           // 16*NCH * 256
    float* kmean = pksum + (size_t)16 * NCH * 256;          // 16 * 256
    unsigned short* kvbT = (unsigned short*)(kmean + (size_t)16 * 256);  // 16*8192

    k0_pw<<<1024, 256, 0, stream>>>(posw, pwb);
    k1_partial<<<BB * NCH, 256, 0, stream>>>(x2, x3, pwb, pkv, pksum);
    k2_reduce<<<512, 256, 0, stream>>>(pkv, pksum, kvbT, kmean);
    k3_out<<<BB * 256, 256, 0, stream>>>(x1, x3, pwb, kvbT, kmean, lw, lb, out);
}